// Round 4
// baseline (799.390 us; speedup 1.0000x reference)
//
#include <hip/hip_runtime.h>
#include <hip/hip_bf16.h>
#include <stdint.h>
#include <string.h>

#define NGRAPH 2048
#define MNODES 128
#define HID 256
#define OUTC 12
#define NEDGE 2097152
#define CAP 2048        // bucket capacity/graph (mean occupancy 1024; overflow p ~ 0)
#define CNT_STRIDE 16   // one counter per 64B line

typedef __attribute__((ext_vector_type(8))) short short8;
typedef __attribute__((ext_vector_type(4))) float v4f;

#define SLICE 64        // hidden columns per block

// XOR-swizzled walk^T layout: row stride 128 elems, 16B chunks permuted by
// low 3 bits of the column -> conflict-free ds_read_b128 / cheap b64 writes.
__device__ __forceinline__ int swz_off(int lcol, int kelem) {
    int chunk = kelem >> 3;
    int within = kelem & 7;
    return (lcol << 7) + (((chunk ^ (lcol & 7)) << 3) | within);
}

__device__ __forceinline__ unsigned pk2(float a, float b) {
    __hip_bfloat162 h = __float22bfloat162_rn(float2{a, b});   // packed RNE cvt
    unsigned u;
    memcpy(&u, &h, 4);
    return u;
}

// ---- bucket edges by graph: 1 packed ushort per edge, atomic slot alloc
__global__ void scatter_edges(const int* __restrict__ ei, unsigned int* __restrict__ cnt,
                              unsigned short* __restrict__ bucket) {
    int e = blockIdx.x * blockDim.x + threadIdx.x;
    if (e >= NEDGE) return;
    int sN = ei[e];
    int dN = ei[NEDGE + e];
    int g = sN >> 7;
    unsigned short pk = (unsigned short)(((sN & 127) << 7) | (dN & 127));
    unsigned slot = atomicAdd(&cnt[g * CNT_STRIDE], 1u);
    if (slot < CAP) bucket[(size_t)g * CAP + slot] = pk;
}

// ---- walk kernel: block = (graph, 64-col slice). Builds 2KB adjacency
// bitmask in LDS from the graph's bucket, A-fragments in registers for all
// 5 iterations, walk^T through swizzled LDS.
__launch_bounds__(256, 4)
__global__ void walk3(const float* __restrict__ x,
                      const float* __restrict__ W,
                      const unsigned int* __restrict__ cnt,
                      const unsigned short* __restrict__ bucket,
                      float* __restrict__ partial) {
    __shared__ unsigned int sBits[MNODES * 4];    // 2KB adjacency bitmask
    __shared__ unsigned short sWT[SLICE * 128];   // 16KB walk^T (swizzled)
    __shared__ float sVs2[2][6][SLICE];           // 3KB per-row-half col sums

    const int bx = blockIdx.x;
    const int g = bx >> 2;
    const int s = bx & 3;
    const int tid = threadIdx.x;
    const int wave = tid >> 6;
    const int lane = tid & 63;
    const int lrow = lane & 15;
    const int quad = lane >> 4;
    const int rhalf = wave >> 1;
    const int r0 = rhalf * 64;
    const int c0 = (wave & 1) * 32;     // col base within slice
    const int cg0 = s * SLICE + c0;     // global col base

    // zero bitmask
    sBits[tid] = 0u;
    sBits[tid + 256] = 0u;

    // ---- X fragments (fp32, C-layout) — issue global loads early
    float xf[4][2][4];
    const float* xg = x + (size_t)g * (MNODES * HID);
#pragma unroll
    for (int rt = 0; rt < 4; rt++)
#pragma unroll
        for (int ct = 0; ct < 2; ct++) {
            int col = cg0 + ct * 16 + lrow;
#pragma unroll
            for (int reg = 0; reg < 4; reg++) {
                int row = r0 + rt * 16 + quad * 4 + reg;
                xf[rt][ct][reg] = xg[row * HID + col];
            }
        }

    // ---- build adjacency bitmask from this graph's edge bucket
    int ec = (int)min(cnt[g * CNT_STRIDE], (unsigned)CAP);
    const unsigned short* bk = bucket + (size_t)g * CAP;
    __syncthreads();   // bitmask zeroed
    for (int e = tid; e < ec; e += 256) {
        unsigned p = bk[e];
        int li = p >> 7, lj = p & 127;
        atomicOr(&sBits[li * 4 + (lj >> 5)], 1u << (lj & 31));
        atomicOr(&sBits[lj * 4 + (li >> 5)], 1u << (li & 31));
    }
    __syncthreads();   // bitmask complete

    // ---- expand bitmask -> A fragments in registers (fixed across iters)
    short8 areg[4][4];  // [rt][ks]
#pragma unroll
    for (int rt = 0; rt < 4; rt++) {
        int row = r0 + rt * 16 + lrow;
#pragma unroll
        for (int ks = 0; ks < 4; ks++) {
            unsigned w = sBits[row * 4 + ks] >> (quad * 8);
            short8 a;
#pragma unroll
            for (int j = 0; j < 8; j++)
                a[j] = (short)(((w >> j) & 1u) ? 0x3F80 : 0);
            areg[rt][ks] = a;
        }
    }

    // ---- init walk1 = X (bf16 into swizzled LDS), v1 col sums
#pragma unroll
    for (int ct = 0; ct < 2; ct++) {
        int lcol = c0 + ct * 16 + lrow;
        float cs = 0.0f;
#pragma unroll
        for (int rt = 0; rt < 4; rt++) {
            int nbase = r0 + rt * 16 + quad * 4;
            uint2 u;
            u.x = pk2(xf[rt][ct][0], xf[rt][ct][1]);
            u.y = pk2(xf[rt][ct][2], xf[rt][ct][3]);
            *(uint2*)&sWT[swz_off(lcol, nbase)] = u;
            cs += xf[rt][ct][0] + xf[rt][ct][1] + xf[rt][ct][2] + xf[rt][ct][3];
        }
        cs += __shfl_xor(cs, 16);
        cs += __shfl_xor(cs, 32);
        if (quad == 0) sVs2[rhalf][0][lcol] = cs;   // same-rhalf waves own disjoint lcol
    }
    __syncthreads();

    // ---- 5 iterations: Y = A@walk (MFMA, A in regs), walk = Y.*X, col sums
    for (int it = 1; it <= 5; it++) {
        v4f acc[4][2];
#pragma unroll
        for (int rt = 0; rt < 4; rt++)
#pragma unroll
            for (int ct = 0; ct < 2; ct++) acc[rt][ct] = (v4f)(0.0f);
#pragma unroll
        for (int ks = 0; ks < 4; ks++) {
            int k0 = ks * 32 + quad * 8;
#pragma unroll
            for (int ct = 0; ct < 2; ct++) {
                short8 bf = *(const short8*)&sWT[swz_off(c0 + ct * 16 + lrow, k0)];
#pragma unroll
                for (int rt = 0; rt < 4; rt++)
                    acc[rt][ct] = __builtin_amdgcn_mfma_f32_16x16x32_bf16(areg[rt][ks], bf, acc[rt][ct], 0, 0, 0);
            }
        }
        __syncthreads();  // all reads done before overwrite
#pragma unroll
        for (int ct = 0; ct < 2; ct++) {
            int lcol = c0 + ct * 16 + lrow;
            float cs = 0.0f;
#pragma unroll
            for (int rt = 0; rt < 4; rt++) {
                float nw0 = acc[rt][ct][0] * xf[rt][ct][0];
                float nw1 = acc[rt][ct][1] * xf[rt][ct][1];
                float nw2 = acc[rt][ct][2] * xf[rt][ct][2];
                float nw3 = acc[rt][ct][3] * xf[rt][ct][3];
                int nbase = r0 + rt * 16 + quad * 4;
                uint2 u;
                u.x = pk2(nw0, nw1);
                u.y = pk2(nw2, nw3);
                *(uint2*)&sWT[swz_off(lcol, nbase)] = u;
                cs += nw0 + nw1 + nw2 + nw3;
            }
            cs += __shfl_xor(cs, 16);
            cs += __shfl_xor(cs, 32);
            if (quad == 0) sVs2[rhalf][it][lcol] = cs;
        }
        __syncthreads();  // walk ready for next iteration (publishes sVs2)
    }

    // ---- per-block partial projection over this 6x64 slice of vs
    if (wave == 0) {
        for (int c = 0; c < OUTC; c++) {
            float p = 0.0f;
            const float* wr = W + c * (6 * HID);
#pragma unroll
            for (int ii = 0; ii < 6; ii++) {
                int i = ii * 64 + lane;
                int k = i >> 6;
                int h = i & 63;
                float v = sVs2[0][k][h] + sVs2[1][k][h];
                p += v * wr[k * HID + s * SLICE + h];
            }
#pragma unroll
            for (int off = 32; off >= 1; off >>= 1) p += __shfl_down(p, off);
            if (lane == 0) partial[bx * OUTC + c] = p;
        }
    }
}

// ---- combine the 4 slice partials + bias
__global__ void combine(const float* __restrict__ partial, const float* __restrict__ bvec,
                        float* __restrict__ out) {
    int i = blockIdx.x * blockDim.x + threadIdx.x;
    if (i >= NGRAPH * OUTC) return;
    int c = i % OUTC;
    int g = i / OUTC;
    float p = bvec[c];
#pragma unroll
    for (int s = 0; s < 4; s++) p += partial[(g * 4 + s) * OUTC + c];
    out[i] = p;
}

extern "C" void kernel_launch(void* const* d_in, const int* in_sizes, int n_in,
                              void* d_out, int out_size, void* d_ws, size_t ws_size,
                              hipStream_t stream) {
    const float* x = (const float*)d_in[0];
    const float* W = (const float*)d_in[1];
    const float* b = (const float*)d_in[2];
    const int* ei = (const int*)d_in[4];
    float* out = (float*)d_out;

    const size_t CNT_BYTES = (size_t)NGRAPH * CNT_STRIDE * sizeof(unsigned int); // 128KB
    const size_t BKT_BYTES = (size_t)NGRAPH * CAP * sizeof(unsigned short);      // 8MB

    unsigned int* cnt = (unsigned int*)d_ws;
    unsigned short* bucket = (unsigned short*)((char*)d_ws + CNT_BYTES);
    float* partial = (float*)((char*)d_ws + CNT_BYTES + BKT_BYTES);

    (void)hipMemsetAsync(cnt, 0, CNT_BYTES, stream);
    scatter_edges<<<NEDGE / 256, 256, 0, stream>>>(ei, cnt, bucket);
    walk3<<<NGRAPH * 4, 256, 0, stream>>>(x, W, cnt, bucket, partial);
    combine<<<(NGRAPH * OUTC + 255) / 256, 256, 0, stream>>>(partial, b, out);
}

// Round 5
// 534.268 us; speedup vs baseline: 1.4962x; 1.4962x over previous
//
#include <hip/hip_runtime.h>
#include <hip/hip_bf16.h>
#include <stdint.h>
#include <string.h>

#define NGRAPH 2048
#define MNODES 128
#define HID 256
#define OUTC 12
#define NEDGE 2097152
#define CAP 2048        // bucket capacity/graph (mean 1024, std ~32; overflow p~0)
#define CNT_STRIDE 16   // one counter per 64B line

typedef __attribute__((ext_vector_type(8))) short short8;
typedef __attribute__((ext_vector_type(4))) float v4f;

#define SLICE 64        // hidden columns per block

// XOR-swizzled walk^T layout: row stride 128 elems, 16B chunks permuted by
// low 3 bits of the column -> conflict-free ds_read_b128 / cheap b64 writes.
__device__ __forceinline__ int swz_off(int lcol, int kelem) {
    int chunk = kelem >> 3;
    int within = kelem & 7;
    return (lcol << 7) + (((chunk ^ (lcol & 7)) << 3) | within);
}

__device__ __forceinline__ unsigned pk2(float a, float b) {
    __hip_bfloat162 h = __float22bfloat162_rn(float2{a, b});   // packed RNE cvt
    unsigned u;
    memcpy(&u, &h, 4);
    return u;
}

// ---- bucket edges by graph: 1 packed ushort per edge, atomic slot alloc
__global__ void scatter_edges(const int* __restrict__ ei, unsigned int* __restrict__ cnt,
                              unsigned short* __restrict__ bucket) {
    int e = blockIdx.x * blockDim.x + threadIdx.x;
    if (e >= NEDGE) return;
    int sN = ei[e];
    int dN = ei[NEDGE + e];
    int g = sN >> 7;
    unsigned short pk = (unsigned short)(((sN & 127) << 7) | (dN & 127));
    unsigned slot = atomicAdd(&cnt[g * CNT_STRIDE], 1u);
    if (slot < CAP) bucket[(size_t)g * CAP + slot] = pk;
}

// ---- walk kernel: block = (graph, 64-col slice). 2KB LDS adjacency bitmask
// from the bucket; A-fragments in registers for all 5 iterations; walk^T
// double-buffered in LDS -> ONE barrier per iteration.
// NOTE __launch_bounds__(256,3): waves/EU=4 caps unified VGPR+AGPR at 128,
// which spills areg (round-4 regression: WRITE_SIZE 0.5->312MB). Keep 3.
__launch_bounds__(256, 3)
__global__ void walk4(const float* __restrict__ x,
                      const float* __restrict__ W,
                      const unsigned int* __restrict__ cnt,
                      const unsigned short* __restrict__ bucket,
                      float* __restrict__ partial) {
    __shared__ unsigned int sBits[MNODES * 4];       // 2KB adjacency bitmask
    __shared__ unsigned short sWT[2][SLICE * 128];   // 2x16KB walk^T (swizzled)
    __shared__ float sVs2[2][6][SLICE];              // 3KB per-row-half col sums

    const int bx = blockIdx.x;
    const int g = bx >> 2;
    const int s = bx & 3;
    const int tid = threadIdx.x;
    const int wave = tid >> 6;
    const int lane = tid & 63;
    const int lrow = lane & 15;
    const int quad = lane >> 4;
    const int rhalf = wave >> 1;
    const int r0 = rhalf * 64;
    const int c0 = (wave & 1) * 32;     // col base within slice
    const int cg0 = s * SLICE + c0;     // global col base

    // zero bitmask
    sBits[tid] = 0u;
    sBits[tid + 256] = 0u;

    // ---- X fragments (fp32, C-layout) — issue global loads early
    float xf[4][2][4];
    const float* xg = x + (size_t)g * (MNODES * HID);
#pragma unroll
    for (int rt = 0; rt < 4; rt++)
#pragma unroll
        for (int ct = 0; ct < 2; ct++) {
            int col = cg0 + ct * 16 + lrow;
#pragma unroll
            for (int reg = 0; reg < 4; reg++) {
                int row = r0 + rt * 16 + quad * 4 + reg;
                xf[rt][ct][reg] = xg[row * HID + col];
            }
        }

    // ---- build adjacency bitmask from this graph's edge bucket
    int ec = (int)min(cnt[g * CNT_STRIDE], (unsigned)CAP);
    const unsigned short* bk = bucket + (size_t)g * CAP;
    __syncthreads();   // bitmask zeroed
    for (int e = tid; e < ec; e += 256) {
        unsigned p = bk[e];
        int li = p >> 7, lj = p & 127;
        atomicOr(&sBits[li * 4 + (lj >> 5)], 1u << (lj & 31));
        atomicOr(&sBits[lj * 4 + (li >> 5)], 1u << (li & 31));
    }
    __syncthreads();   // bitmask complete

    // ---- expand bitmask -> A fragments in registers (fixed across iters)
    short8 areg[4][4];  // [rt][ks]
#pragma unroll
    for (int rt = 0; rt < 4; rt++) {
        int row = r0 + rt * 16 + lrow;
#pragma unroll
        for (int ks = 0; ks < 4; ks++) {
            unsigned w = sBits[row * 4 + ks] >> (quad * 8);
            short8 a;
#pragma unroll
            for (int j = 0; j < 8; j++)
                a[j] = (short)(((w >> j) & 1u) ? 0x3F80 : 0);
            areg[rt][ks] = a;
        }
    }

    // ---- init walk1 = X (bf16 into swizzled LDS buf 0), v1 col sums
#pragma unroll
    for (int ct = 0; ct < 2; ct++) {
        int lcol = c0 + ct * 16 + lrow;
        float cs = 0.0f;
#pragma unroll
        for (int rt = 0; rt < 4; rt++) {
            int nbase = r0 + rt * 16 + quad * 4;
            uint2 u;
            u.x = pk2(xf[rt][ct][0], xf[rt][ct][1]);
            u.y = pk2(xf[rt][ct][2], xf[rt][ct][3]);
            *(uint2*)&sWT[0][swz_off(lcol, nbase)] = u;
            cs += xf[rt][ct][0] + xf[rt][ct][1] + xf[rt][ct][2] + xf[rt][ct][3];
        }
        cs += __shfl_xor(cs, 16);
        cs += __shfl_xor(cs, 32);
        if (quad == 0) sVs2[rhalf][0][lcol] = cs;   // same-rhalf waves own disjoint lcol
    }
    __syncthreads();

    // ---- 5 iterations, double-buffered: read sWT[p], write sWT[p^1].
    // One barrier per iteration (end): publishes writes for next iter's reads;
    // WAR on sWT[p^1] is fenced by the PREVIOUS iteration's barrier.
#pragma unroll
    for (int it = 1; it <= 5; it++) {
        const int p = (it - 1) & 1;
        v4f acc[4][2];
#pragma unroll
        for (int rt = 0; rt < 4; rt++)
#pragma unroll
            for (int ct = 0; ct < 2; ct++) acc[rt][ct] = (v4f)(0.0f);
#pragma unroll
        for (int ks = 0; ks < 4; ks++) {
            int k0 = ks * 32 + quad * 8;
#pragma unroll
            for (int ct = 0; ct < 2; ct++) {
                short8 bf = *(const short8*)&sWT[p][swz_off(c0 + ct * 16 + lrow, k0)];
#pragma unroll
                for (int rt = 0; rt < 4; rt++)
                    acc[rt][ct] = __builtin_amdgcn_mfma_f32_16x16x32_bf16(areg[rt][ks], bf, acc[rt][ct], 0, 0, 0);
            }
        }
#pragma unroll
        for (int ct = 0; ct < 2; ct++) {
            int lcol = c0 + ct * 16 + lrow;
            float cs = 0.0f;
#pragma unroll
            for (int rt = 0; rt < 4; rt++) {
                float nw0 = acc[rt][ct][0] * xf[rt][ct][0];
                float nw1 = acc[rt][ct][1] * xf[rt][ct][1];
                float nw2 = acc[rt][ct][2] * xf[rt][ct][2];
                float nw3 = acc[rt][ct][3] * xf[rt][ct][3];
                int nbase = r0 + rt * 16 + quad * 4;
                uint2 u;
                u.x = pk2(nw0, nw1);
                u.y = pk2(nw2, nw3);
                *(uint2*)&sWT[p ^ 1][swz_off(lcol, nbase)] = u;
                cs += nw0 + nw1 + nw2 + nw3;
            }
            cs += __shfl_xor(cs, 16);
            cs += __shfl_xor(cs, 32);
            if (quad == 0) sVs2[rhalf][it][lcol] = cs;
        }
        __syncthreads();
    }

    // ---- per-block partial projection over this 6x64 slice of vs
    if (wave == 0) {
        for (int c = 0; c < OUTC; c++) {
            float p = 0.0f;
            const float* wr = W + c * (6 * HID);
#pragma unroll
            for (int ii = 0; ii < 6; ii++) {
                int i = ii * 64 + lane;
                int k = i >> 6;
                int h = i & 63;
                float v = sVs2[0][k][h] + sVs2[1][k][h];
                p += v * wr[k * HID + s * SLICE + h];
            }
#pragma unroll
            for (int off = 32; off >= 1; off >>= 1) p += __shfl_down(p, off);
            if (lane == 0) partial[bx * OUTC + c] = p;
        }
    }
}

// ---- combine the 4 slice partials + bias
__global__ void combine(const float* __restrict__ partial, const float* __restrict__ bvec,
                        float* __restrict__ out) {
    int i = blockIdx.x * blockDim.x + threadIdx.x;
    if (i >= NGRAPH * OUTC) return;
    int c = i % OUTC;
    int g = i / OUTC;
    float p = bvec[c];
#pragma unroll
    for (int s = 0; s < 4; s++) p += partial[(g * 4 + s) * OUTC + c];
    out[i] = p;
}

extern "C" void kernel_launch(void* const* d_in, const int* in_sizes, int n_in,
                              void* d_out, int out_size, void* d_ws, size_t ws_size,
                              hipStream_t stream) {
    const float* x = (const float*)d_in[0];
    const float* W = (const float*)d_in[1];
    const float* b = (const float*)d_in[2];
    const int* ei = (const int*)d_in[4];
    float* out = (float*)d_out;

    const size_t CNT_BYTES = (size_t)NGRAPH * CNT_STRIDE * sizeof(unsigned int); // 128KB
    const size_t BKT_BYTES = (size_t)NGRAPH * CAP * sizeof(unsigned short);      // 8MB

    unsigned int* cnt = (unsigned int*)d_ws;
    unsigned short* bucket = (unsigned short*)((char*)d_ws + CNT_BYTES);
    float* partial = (float*)((char*)d_ws + CNT_BYTES + BKT_BYTES);

    (void)hipMemsetAsync(cnt, 0, CNT_BYTES, stream);
    scatter_edges<<<NEDGE / 256, 256, 0, stream>>>(ei, cnt, bucket);
    walk4<<<NGRAPH * 4, 256, 0, stream>>>(x, W, cnt, bucket, partial);
    combine<<<(NGRAPH * OUTC + 255) / 256, 256, 0, stream>>>(partial, b, out);
}